// Round 6
// baseline (3758.886 us; speedup 1.0000x reference)
//
#include <hip/hip_runtime.h>
#include <hip/hip_bf16.h>

typedef __bf16 bf16_t;
typedef __bf16 bf16x8 __attribute__((ext_vector_type(8)));
typedef float f32x4 __attribute__((ext_vector_type(4)));

#define Bn 8
#define Tn 2048
#define Cn 2048
#define Hn 32
#define HSn 64
#define CT 32

static const long SZ = (long)Bn * Tn * Cn;   // 33,554,432 elements

__device__ __forceinline__ void g2l16(const void* g, void* l) {
  __builtin_amdgcn_global_load_lds((const __attribute__((address_space(1))) void*)g,
                                   (__attribute__((address_space(3))) void*)l,
                                   16, 0, 0);
}

// ---------------------------------------------------------------------------
// Weight transpose + fp32 -> split bf16 hi/lo: Oh/Ol[n][k] = split(W[k][n])
// ---------------------------------------------------------------------------
__global__ __launch_bounds__(256)
void transps(const float* w0, const float* w1, const float* w2,
             const float* w3, const float* w4, bf16_t* oh, bf16_t* ol)
{
  const float* Ws[5] = {w0, w1, w2, w3, w4};
  const float* W = Ws[blockIdx.z];
  const long base = (long)blockIdx.z * ((long)Cn * Cn);
  __shared__ float tile[64][65];
  const int xx = threadIdx.x & 63;
  const int y4 = threadIdx.x >> 6;
  const int bx = blockIdx.x * 64, by = blockIdx.y * 64;
#pragma unroll
  for (int i = 0; i < 16; ++i) {
    int row = i * 4 + y4;
    tile[row][xx] = W[(long)(by + row) * Cn + bx + xx];
  }
  __syncthreads();
#pragma unroll
  for (int i = 0; i < 16; ++i) {
    int row = i * 4 + y4;
    float v = tile[xx][row];
    bf16_t hi = (bf16_t)v;
    long o = base + (long)(bx + row) * Cn + by + xx;
    oh[o] = hi;
    ol[o] = (bf16_t)(v - (float)hi);
  }
}

// ---------------------------------------------------------------------------
// Split x split GEMM: C[16384,2048] = A * B, B given transposed split bf16
// hi/lo [N,K]. A either computed on the fly (amode 0: time-mix of fp32 x,
// split to hi/lo in registers) or read from split bf16 slots (amode 1).
// 128x128 tile, BK=32, 3x mfma_f32_16x16x32_bf16 per fragment
// (al*bh + ah*bl + ah*bh; lo*lo ~ 2^-18, skipped).
// emode 0: bf16 store to Cp.     emode 3: split store hi->Gh, lo->Gl.
// emode 1: zg = silu(acc)*(Zh+Zl), split store hi->Gh, lo->Gl.
// emode 2: fp32 store to Cp.
// ---------------------------------------------------------------------------
__global__ __launch_bounds__(256)
void gemmx(const float* __restrict__ X, const float* __restrict__ tm,
           const bf16_t* __restrict__ Ah, const bf16_t* __restrict__ Al,
           const bf16_t* __restrict__ BTh, const bf16_t* __restrict__ BTl,
           void* __restrict__ Cp,
           const bf16_t* __restrict__ Zh, const bf16_t* __restrict__ Zl,
           bf16_t* __restrict__ Gh, bf16_t* __restrict__ Gl,
           int amode, int emode)
{
  __shared__ __align__(16) bf16_t lAh[128 * 32];
  __shared__ __align__(16) bf16_t lAl[128 * 32];
  __shared__ __align__(16) bf16_t lBh[128 * 32];
  __shared__ __align__(16) bf16_t lBl[128 * 32];

  const int tid = threadIdx.x;
  const int wave = tid >> 6;
  const int lane = tid & 63;
  const long m0 = (long)blockIdx.y * 128;
  const int n0 = blockIdx.x * 128;
  const int wm = (wave & 1) * 64;
  const int wn = (wave >> 1) * 64;

  // staging: 2 chunks of 16B (8 elems) per thread per operand over 128x32
  const int e0 = (wave * 2 + 0) * 512 + lane * 8;
  const int e1 = (wave * 2 + 1) * 512 + lane * 8;
  const int r0 = e0 >> 5, c0 = e0 & 31;
  const int r1 = e1 >> 5, c1 = e1 & 31;
  const long aoff0 = (m0 + r0) * Cn + c0;
  const long aoff1 = (m0 + r1) * Cn + c1;
  const long boff0 = (long)(n0 + r0) * Cn + c0;
  const long boff1 = (long)(n0 + r1) * Cn + c1;
  const int t0 = (int)((m0 + r0) & (Tn - 1));   // timestep of staged row 0
  const int t1 = (int)((m0 + r1) & (Tn - 1));

  f32x4 acc[4][4] = {};
  const int kg = lane >> 4;
  const int lr = lane & 15;

  for (int k0 = 0; k0 < Cn; k0 += 32) {
    if (amode == 0) {
      // on-the-fly mix + split for the A tile
      float xf[16], pf[16], tf[16];
      *(f32x4*)&xf[0]  = *(const f32x4*)&X[aoff0 + k0];
      *(f32x4*)&xf[4]  = *(const f32x4*)&X[aoff0 + k0 + 4];
      *(f32x4*)&xf[8]  = *(const f32x4*)&X[aoff1 + k0];
      *(f32x4*)&xf[12] = *(const f32x4*)&X[aoff1 + k0 + 4];
      if (t0 > 0) {
        *(f32x4*)&pf[0] = *(const f32x4*)&X[aoff0 - Cn + k0];
        *(f32x4*)&pf[4] = *(const f32x4*)&X[aoff0 - Cn + k0 + 4];
      } else {
#pragma unroll
        for (int q = 0; q < 8; ++q) pf[q] = 0.f;
      }
      if (t1 > 0) {
        *(f32x4*)&pf[8]  = *(const f32x4*)&X[aoff1 - Cn + k0];
        *(f32x4*)&pf[12] = *(const f32x4*)&X[aoff1 - Cn + k0 + 4];
      } else {
#pragma unroll
        for (int q = 8; q < 16; ++q) pf[q] = 0.f;
      }
      *(f32x4*)&tf[0]  = *(const f32x4*)&tm[k0 + c0];
      *(f32x4*)&tf[4]  = *(const f32x4*)&tm[k0 + c0 + 4];
      *(f32x4*)&tf[8]  = *(const f32x4*)&tm[k0 + c1];
      *(f32x4*)&tf[12] = *(const f32x4*)&tm[k0 + c1 + 4];
      bf16x8 h0, l0, h1, l1;
#pragma unroll
      for (int q = 0; q < 8; ++q) {
        float o = pf[q] + tf[q] * (xf[q] - pf[q]);
        bf16_t hi = (bf16_t)o;
        h0[q] = hi; l0[q] = (bf16_t)(o - (float)hi);
      }
#pragma unroll
      for (int q = 0; q < 8; ++q) {
        float o = pf[8 + q] + tf[8 + q] * (xf[8 + q] - pf[8 + q]);
        bf16_t hi = (bf16_t)o;
        h1[q] = hi; l1[q] = (bf16_t)(o - (float)hi);
      }
      *(bf16x8*)&lAh[e0] = h0; *(bf16x8*)&lAl[e0] = l0;
      *(bf16x8*)&lAh[e1] = h1; *(bf16x8*)&lAl[e1] = l1;
    } else {
      g2l16(Ah + aoff0 + k0, &lAh[e0]);
      g2l16(Ah + aoff1 + k0, &lAh[e1]);
      g2l16(Al + aoff0 + k0, &lAl[e0]);
      g2l16(Al + aoff1 + k0, &lAl[e1]);
    }
    g2l16(BTh + boff0 + k0, &lBh[e0]);
    g2l16(BTh + boff1 + k0, &lBh[e1]);
    g2l16(BTl + boff0 + k0, &lBl[e0]);
    g2l16(BTl + boff1 + k0, &lBl[e1]);
    __syncthreads();   // drains vmcnt + lgkmcnt -> LDS populated
    bf16x8 ah[4], al[4], bh[4], bl[4];
#pragma unroll
    for (int t = 0; t < 4; ++t) {
      ah[t] = *(const bf16x8*)&lAh[(wm + t * 16 + lr) * 32 + kg * 8];
      al[t] = *(const bf16x8*)&lAl[(wm + t * 16 + lr) * 32 + kg * 8];
      bh[t] = *(const bf16x8*)&lBh[(wn + t * 16 + lr) * 32 + kg * 8];
      bl[t] = *(const bf16x8*)&lBl[(wn + t * 16 + lr) * 32 + kg * 8];
    }
#pragma unroll
    for (int i = 0; i < 4; ++i)
#pragma unroll
      for (int j = 0; j < 4; ++j) {
        acc[i][j] = __builtin_amdgcn_mfma_f32_16x16x32_bf16(al[i], bh[j], acc[i][j], 0, 0, 0);
        acc[i][j] = __builtin_amdgcn_mfma_f32_16x16x32_bf16(ah[i], bl[j], acc[i][j], 0, 0, 0);
        acc[i][j] = __builtin_amdgcn_mfma_f32_16x16x32_bf16(ah[i], bh[j], acc[i][j], 0, 0, 0);
      }
    __syncthreads();   // protect LDS from next iteration's staging
  }

  // C/D layout: col = lane&15, row = (lane>>4)*4 + reg   [m89-verified]
  const int qr = lane >> 4;
  const int cn = lane & 15;
#pragma unroll
  for (int i = 0; i < 4; ++i) {
#pragma unroll
    for (int j = 0; j < 4; ++j) {
#pragma unroll
      for (int rg = 0; rg < 4; ++rg) {
        long row = m0 + wm + i * 16 + qr * 4 + rg;
        int col = n0 + wn + j * 16 + cn;
        long off = row * Cn + col;
        float vv = acc[i][j][rg];
        if (emode == 0) {
          ((bf16_t*)Cp)[off] = (bf16_t)vv;
        } else if (emode == 1) {
          float z = (float)Zh[off] + (float)Zl[off];
          float zg = vv / (1.f + __expf(-vv)) * z;
          bf16_t hi = (bf16_t)zg;
          Gh[off] = hi;
          Gl[off] = (bf16_t)(zg - (float)hi);
        } else if (emode == 2) {
          ((float*)Cp)[off] = vv;
        } else {   // emode 3: split store
          bf16_t hi = (bf16_t)vv;
          Gh[off] = hi;
          Gl[off] = (bf16_t)(vv - (float)hi);
        }
      }
    }
  }
}

// ---------------------------------------------------------------------------
// wkv5 recurrence + fused /8 + GroupNorm(64, two-pass) + ln scale/shift.
// One block per (b,h). Thread (j=tid>>2, ic=tid&3) owns S[i0..i0+15][j] fp32.
// r (split hi+lo), k, v staged per 32-step chunk in LDS (fp32), double-
// buffered with register prefetch. z written SPLIT hi/lo over rh-slot/k-slot
// (columns this block already consumed; prefetch runs 2 chunks ahead behind
// the two block barriers).
// ---------------------------------------------------------------------------
__global__ __launch_bounds__(256)
void wkv5(const bf16_t* Rh, const bf16_t* __restrict__ Rl,
          const bf16_t* Km, const bf16_t* __restrict__ Vm,
          const float* __restrict__ decay, const float* __restrict__ faaaa,
          const float* __restrict__ lw, const float* __restrict__ lb,
          bf16_t* Zh, bf16_t* Zl)
{
  const int bh = blockIdx.x;
  const int b = bh >> 5;          // H = 32
  const int h = bh & 31;
  const int tid = threadIdx.x;
  const int j = tid >> 2;
  const int ic = tid & 3;
  const int i0 = ic * 16;

  float w[16], u[16], S[16];
#pragma unroll
  for (int q = 0; q < 16; ++q) {
    w[q] = expf(-expf(decay[h * 64 + i0 + q]));
    u[q] = faaaa[h * 64 + i0 + q];
    S[q] = 0.f;
  }

  __shared__ __align__(16) float sR[2][CT * 64];
  __shared__ __align__(16) float sK[2][CT * 64];
  __shared__ __align__(16) float sV[2][CT * 64];
  __shared__ __align__(16) float sY[CT * 64];

  const int e = tid * 8;
  const int tl = e >> 6;
  const int cc = e & 63;
  const long gbase = (long)b * Tn * Cn + h * 64 + cc;

  const int wv = tid >> 6;
  const int ln = tid & 63;
  const float lwv = lw[h * 64 + ln];
  const float lbv = lb[h * 64 + ln];

  bf16x8 prh, prl, pk, pv;
  auto issue = [&](int cch) {
    const long g = gbase + (long)(cch * CT + tl) * Cn;
    prh = *(const bf16x8*)&Rh[g];
    prl = *(const bf16x8*)&Rl[g];
    pk  = *(const bf16x8*)&Km[g];
    pv  = *(const bf16x8*)&Vm[g];
  };
  auto commit = [&](int buf) {
#pragma unroll
    for (int q = 0; q < 8; ++q) {
      sR[buf][e + q] = (float)prh[q] + (float)prl[q];
      sK[buf][e + q] = (float)pk[q];
      sV[buf][e + q] = (float)pv[q];
    }
  };

  issue(0); commit(0);
  __syncthreads();
  issue(1);

  const int NC = Tn / CT;   // 64
  for (int cch = 0; cch < NC; ++cch) {
    const int buf = cch & 1;
#pragma unroll 4
    for (int t = 0; t < CT; ++t) {
      float rr[16], kk[16];
#pragma unroll
      for (int q = 0; q < 4; ++q) {
        *(f32x4*)&rr[q * 4] = *(const f32x4*)&sR[buf][t * 64 + i0 + q * 4];
        *(f32x4*)&kk[q * 4] = *(const f32x4*)&sK[buf][t * 64 + i0 + q * 4];
      }
      float vj = sV[buf][t * 64 + j];
      float yp = 0.f, ap = 0.f;
#pragma unroll
      for (int q = 0; q < 16; ++q) {
        float kv = kk[q] * vj;
        yp += rr[q] * S[q];
        ap += (rr[q] * u[q]) * kk[q];
        S[q] = w[q] * S[q] + kv;
      }
      yp += __shfl_xor(yp, 1); yp += __shfl_xor(yp, 2);
      ap += __shfl_xor(ap, 1); ap += __shfl_xor(ap, 2);
      if (ic == 0) sY[t * 64 + j] = (yp + ap * vj) * 0.125f;
    }
    if (cch + 1 < NC) commit((cch + 1) & 1);
    __syncthreads();
    if (cch + 2 < NC) issue(cch + 2);

    const long zrow0 = ((long)b * Tn + (long)cch * CT) * Cn + h * 64 + ln;
#pragma unroll
    for (int q = 0; q < 8; ++q) {
      const int t = wv * 8 + q;
      float val = sY[t * 64 + ln];
      float s = val;
#pragma unroll
      for (int off = 1; off < 64; off <<= 1) s += __shfl_xor(s, off);
      float mu = s * (1.f / 64.f);
      float dv = val - mu;
      float vs = dv * dv;
#pragma unroll
      for (int off = 1; off < 64; off <<= 1) vs += __shfl_xor(vs, off);
      float var = vs * (1.f / 64.f);           // >= 0 by construction
      float rs = rsqrtf(var + 1e-5f);
      float zv = dv * rs * lwv + lbv;
      bf16_t zh = (bf16_t)zv;
      Zh[zrow0 + (long)t * Cn] = zh;
      Zl[zrow0 + (long)t * Cn] = (bf16_t)(zv - (float)zh);
    }
    __syncthreads();
  }
}

// ---------------------------------------------------------------------------
extern "C" void kernel_launch(void* const* d_in, const int* in_sizes, int n_in,
                              void* d_out, int out_size, void* d_ws, size_t ws_size,
                              hipStream_t stream)
{
  const float* x    = (const float*)d_in[0];
  const float* tmk  = (const float*)d_in[1];
  const float* tmv  = (const float*)d_in[2];
  const float* tmr  = (const float*)d_in[3];
  const float* tmg  = (const float*)d_in[4];
  const float* tdec = (const float*)d_in[5];
  const float* tfaa = (const float*)d_in[6];
  const float* Wr   = (const float*)d_in[7];
  const float* Wk   = (const float*)d_in[8];
  const float* Wv   = (const float*)d_in[9];
  const float* Wg   = (const float*)d_in[10];
  const float* Wo   = (const float*)d_in[11];
  const float* lnw  = (const float*)d_in[12];
  const float* lnb  = (const float*)d_in[13];

  // ws layout (218.1 MB):
  //   [0, 41.9MB)      wTh : 5 transposed weight hi
  //   [41.9, 83.9MB)   wTl : 5 transposed weight lo
  //   sl0: v,    then zg_hi
  //   sl1: r_lo, then zg_lo
  // d_out (134 MB fp32 = 2 bf16 slots):
  //   d0a: r_hi, then z_hi;  d0b: k, then z_lo;  finally fp32 out.
  char* ws = (char*)d_ws;
  const long WSZ = (long)Cn * Cn;
  const long SZB = SZ * 2;                  // 67,108,864 B per bf16 slot
  bf16_t* wTh = (bf16_t*)ws;
  bf16_t* wTl = (bf16_t*)(ws + 5 * WSZ * 2);
  bf16_t* sl0 = (bf16_t*)(ws + 10 * WSZ * 2);
  bf16_t* sl1 = (bf16_t*)(ws + 10 * WSZ * 2 + SZB);
  bf16_t* d0a = (bf16_t*)d_out;
  bf16_t* d0b = (bf16_t*)d_out + SZ;

  const dim3 gGrid(16, 128, 1);

  transps<<<dim3(32, 32, 5), 256, 0, stream>>>(Wr, Wk, Wv, Wg, Wo, wTh, wTl);

  // r = mix(x,tmr) @ Wr, split -> hi d0a, lo sl1
  gemmx<<<gGrid, 256, 0, stream>>>(x, tmr, nullptr, nullptr,
                                   wTh + 0 * WSZ, wTl + 0 * WSZ, nullptr,
                                   nullptr, nullptr, d0a, sl1, 0, 3);
  // k = mix(x,tmk) @ Wk -> bf16 d0b
  gemmx<<<gGrid, 256, 0, stream>>>(x, tmk, nullptr, nullptr,
                                   wTh + 1 * WSZ, wTl + 1 * WSZ, d0b,
                                   nullptr, nullptr, nullptr, nullptr, 0, 0);
  // v = mix(x,tmv) @ Wv -> bf16 sl0
  gemmx<<<gGrid, 256, 0, stream>>>(x, tmv, nullptr, nullptr,
                                   wTh + 2 * WSZ, wTl + 2 * WSZ, sl0,
                                   nullptr, nullptr, nullptr, nullptr, 0, 0);

  // wkv5 + /8 + groupnorm -> z split: hi over d0a (r_hi), lo over d0b (k)
  wkv5<<<256, 256, 0, stream>>>(d0a, sl1, d0b, sl0, tdec, tfaa, lnw, lnb,
                                d0a, d0b);

  // zg = silu(mix(x,tmg) @ Wg) * (z_hi+z_lo), split -> hi sl0, lo sl1
  gemmx<<<gGrid, 256, 0, stream>>>(x, tmg, nullptr, nullptr,
                                   wTh + 3 * WSZ, wTl + 3 * WSZ, nullptr,
                                   d0a, d0b, sl0, sl1, 0, 1);

  // out = (zg_hi+zg_lo) @ Wo -> fp32 d_out
  gemmx<<<gGrid, 256, 0, stream>>>(nullptr, nullptr, sl0, sl1,
                                   wTh + 4 * WSZ, wTl + 4 * WSZ, d_out,
                                   nullptr, nullptr, nullptr, nullptr, 1, 2);
}